// Round 1
// baseline (1858.820 us; speedup 1.0000x reference)
//
#include <hip/hip_runtime.h>

#define EPS 1e-12f
#define NEG_INF (-3.0e38f)

constexpr int B = 128;     // queries
constexpr int D = 128;     // dim
constexpr int K_TOP = 10;
constexpr int TILE_N = 128;
constexpr int LDT = 132;   // padded LDS row stride in floats (132%32==4 -> bank rotation)
constexpr int SEGS = 8;

// ---------------- 1. query normalization ----------------
// grid: B blocks x 64 threads (one wave per query)
__global__ void qnorm_kernel(const float* __restrict__ q, float* __restrict__ qn) {
    int b = blockIdx.x;
    int l = threadIdx.x;           // 0..63
    const float* row = q + b * D;
    float2 v = *(const float2*)(row + 2 * l);
    float s = v.x * v.x + v.y * v.y;
#pragma unroll
    for (int off = 32; off > 0; off >>= 1) s += __shfl_xor(s, off);
    float norm = fmaxf(sqrtf(s), EPS);
    float* orow = qn + b * D;
    orow[2 * l]     = v.x / norm;
    orow[2 * l + 1] = v.y / norm;
}

// ---------------- 2. similarity GEMM ----------------
// block: 256 threads, computes a 128(query) x 128(db) tile.
// qn (normalized queries) and raw db tile staged in LDS; db row inv-norms
// computed in-block and folded in at store time.
__global__ __launch_bounds__(256, 1)
void simgemm_kernel(const float* __restrict__ qn, const float* __restrict__ db,
                    float* __restrict__ sim, int N) {
    __shared__ __align__(16) float qs[B * LDT];
    __shared__ __align__(16) float bs[TILE_N * LDT];
    __shared__ float inv_db[TILE_N];

    const int t  = threadIdx.x;
    const int n0 = blockIdx.x * TILE_N;

    // stage qn: 128x128 floats = 4096 float4, 16 per thread, coalesced
#pragma unroll
    for (int it = 0; it < 16; ++it) {
        int f   = t + 256 * it;       // float4 index
        int row = f >> 5, c4 = f & 31;
        float4 v = *(const float4*)(qn + row * D + c4 * 4);
        *(float4*)(&qs[row * LDT + c4 * 4]) = v;
    }
    // stage db tile (bounds-guarded, zero-fill OOB rows)
#pragma unroll
    for (int it = 0; it < 16; ++it) {
        int f   = t + 256 * it;
        int row = f >> 5, c4 = f & 31;
        int gr  = n0 + row;
        float4 v = make_float4(0.f, 0.f, 0.f, 0.f);
        if (gr < N) v = *(const float4*)(db + (size_t)gr * D + c4 * 4);
        *(float4*)(&bs[row * LDT + c4 * 4]) = v;
    }
    __syncthreads();

    // per-row inv norms (threads 0..127), once per block
    if (t < TILE_N) {
        float s = 0.f;
#pragma unroll
        for (int c4 = 0; c4 < 32; ++c4) {
            float4 v = *(const float4*)(&bs[t * LDT + c4 * 4]);
            s += v.x * v.x + v.y * v.y + v.z * v.z + v.w * v.w;
        }
        inv_db[t] = 1.0f / fmaxf(sqrtf(s), EPS);
    }
    __syncthreads();

    const int tx = t & 15, ty = t >> 4;   // 16x16 thread grid
    float acc[8][8];
#pragma unroll
    for (int i = 0; i < 8; ++i)
#pragma unroll
        for (int j = 0; j < 8; ++j) acc[i][j] = 0.f;

#pragma unroll 2
    for (int k4 = 0; k4 < 32; ++k4) {
        float4 a[8], bb[8];
#pragma unroll
        for (int i = 0; i < 8; ++i) a[i]  = *(const float4*)(&qs[(ty + 16 * i) * LDT + k4 * 4]);
#pragma unroll
        for (int j = 0; j < 8; ++j) bb[j] = *(const float4*)(&bs[(tx + 16 * j) * LDT + k4 * 4]);
#pragma unroll
        for (int i = 0; i < 8; ++i)
#pragma unroll
            for (int j = 0; j < 8; ++j) {
                acc[i][j] = fmaf(a[i].x, bb[j].x, acc[i][j]);
                acc[i][j] = fmaf(a[i].y, bb[j].y, acc[i][j]);
                acc[i][j] = fmaf(a[i].z, bb[j].z, acc[i][j]);
                acc[i][j] = fmaf(a[i].w, bb[j].w, acc[i][j]);
            }
    }

#pragma unroll
    for (int i = 0; i < 8; ++i) {
        int m = ty + 16 * i;
#pragma unroll
        for (int j = 0; j < 8; ++j) {
            int n  = tx + 16 * j;
            int gn = n0 + n;
            if (gn < N) sim[(size_t)m * N + gn] = acc[i][j] * inv_db[n];
        }
    }
}

// ---------------- 3. top-k phase 1: per (query, segment) block top-10 ----------------
// grid: B*SEGS blocks x 256 threads
__global__ __launch_bounds__(256)
void topk_phase1(const float* __restrict__ sim, float* __restrict__ cand_val,
                 int* __restrict__ cand_idx, int N) {
    const int q   = blockIdx.x >> 3;
    const int seg = blockIdx.x & 7;
    const int t   = threadIdx.x;
    const float* row = sim + (size_t)q * N;

    const int start = (int)(((long long)N * seg) / SEGS);      // multiples of 4 for N=1e6
    const int end   = (int)(((long long)N * (seg + 1)) / SEGS);
    const int s4 = start >> 2, e4 = end >> 2;

    float v[10];
    int   ix[10];
#pragma unroll
    for (int j = 0; j < 10; ++j) { v[j] = NEG_INF; ix[j] = 0x7fffffff; }
    float vmin = NEG_INF;

    for (int f = s4 + t; f < e4; f += 256) {
        float4 x = *(const float4*)(row + 4 * f);
        int n = 4 * f;
#pragma unroll
        for (int c = 0; c < 4; ++c) {
            float xv = (c == 0) ? x.x : (c == 1) ? x.y : (c == 2) ? x.z : x.w;
            if (xv > vmin) {
                // branchless constant-index sorted insert (desc, stable: ties keep lower idx)
#pragma unroll
                for (int j = 9; j >= 1; --j) {
                    if (v[j - 1] < xv)      { v[j] = v[j - 1]; ix[j] = ix[j - 1]; }
                    else if (v[j] < xv)     { v[j] = xv;       ix[j] = n + c;     }
                }
                if (v[0] < xv)              { v[0] = xv;       ix[0] = n + c;     }
                vmin = v[9];
            }
        }
    }

    // block merge: 256 threads x 10 candidates -> top-10
    __shared__ float lv[2560];
    __shared__ int   li[2560];
#pragma unroll
    for (int j = 0; j < 10; ++j) { lv[t * 10 + j] = v[j]; li[t * 10 + j] = ix[j]; }
    __syncthreads();

    __shared__ float rv[256];
    __shared__ int   ri[256];
    __shared__ int   rs[256];
    for (int r = 0; r < K_TOP; ++r) {
        float bv = NEG_INF; int bi = 0x7fffffff; int bslot = t * 10;
#pragma unroll
        for (int j = 0; j < 10; ++j) {
            int s = t * 10 + j;
            float vv = lv[s]; int ii = li[s];
            if (vv > bv || (vv == bv && ii < bi)) { bv = vv; bi = ii; bslot = s; }
        }
        rv[t] = bv; ri[t] = bi; rs[t] = bslot;
        __syncthreads();
        for (int s = 128; s > 0; s >>= 1) {
            if (t < s) {
                if (rv[t + s] > rv[t] || (rv[t + s] == rv[t] && ri[t + s] < ri[t])) {
                    rv[t] = rv[t + s]; ri[t] = ri[t + s]; rs[t] = rs[t + s];
                }
            }
            __syncthreads();
        }
        if (t == 0) {
            cand_val[blockIdx.x * K_TOP + r] = rv[0];
            cand_idx[blockIdx.x * K_TOP + r] = ri[0];
            lv[rs[0]] = NEG_INF;   // invalidate winner
        }
        __syncthreads();
    }
}

// ---------------- 4. top-k phase 2: merge SEGS*10 candidates per query ----------------
// grid: 1 block x B threads; thread b handles query b
__global__ void topk_phase2(const float* __restrict__ cand_val,
                            const int* __restrict__ cand_idx,
                            float* __restrict__ out_idx) {
    int q = threadIdx.x;
    float cv[SEGS * K_TOP];
    int   ci[SEGS * K_TOP];
#pragma unroll
    for (int j = 0; j < SEGS * K_TOP; ++j) {
        cv[j] = cand_val[q * SEGS * K_TOP + j];
        ci[j] = cand_idx[q * SEGS * K_TOP + j];
    }
    for (int r = 0; r < K_TOP; ++r) {
        float bv = NEG_INF; int bi = 0x7fffffff; int bs = 0;
        for (int j = 0; j < SEGS * K_TOP; ++j) {
            if (cv[j] > bv || (cv[j] == bv && ci[j] < bi)) { bv = cv[j]; bi = ci[j]; bs = j; }
        }
        cv[bs] = NEG_INF;
        out_idx[q * K_TOP + r] = (float)bi;
    }
}

extern "C" void kernel_launch(void* const* d_in, const int* in_sizes, int n_in,
                              void* d_out, int out_size, void* d_ws, size_t ws_size,
                              hipStream_t stream) {
    const float* vec = (const float*)d_in[0];   // [B, D] fp32
    const float* db  = (const float*)d_in[1];   // [N, D] fp32
    const int N = in_sizes[1] / D;              // 1,000,000

    float* out     = (float*)d_out;
    float* out_idx = out;                       // [B, K_TOP] indices (as float)
    float* sim     = out + B * K_TOP;           // [B, N] similarities

    float* ws       = (float*)d_ws;
    float* qn       = ws;                        // 16384 floats
    float* cand_val = ws + 16384;                // B*SEGS*K_TOP = 10240 floats
    int*   cand_idx = (int*)(ws + 16384 + B * SEGS * K_TOP);

    qnorm_kernel<<<B, 64, 0, stream>>>(vec, qn);
    simgemm_kernel<<<(N + TILE_N - 1) / TILE_N, 256, 0, stream>>>(qn, db, sim, N);
    topk_phase1<<<B * SEGS, 256, 0, stream>>>(sim, cand_val, cand_idx, N);
    topk_phase2<<<1, B, 0, stream>>>(cand_val, cand_idx, out_idx);
}